// Round 3
// baseline (552.693 us; speedup 1.0000x reference)
//
#include <hip/hip_runtime.h>
#include <stdint.h>

// Problem constants
#define L_    8192
#define N_    8
#define L2_   2048
#define K_    16
#define CAP   20   // per-(query,slice) survivor capacity (>=16 + tie slack)

typedef unsigned int uint;
typedef unsigned short ushort;
typedef unsigned long long u64;

// round-to-nearest-even f32 -> bf16 (monotone)
__device__ __forceinline__ ushort f2b(float f){
  uint u = __float_as_uint(f);
  return (ushort)((u + 0x7FFFu + ((u >> 16) & 1u)) >> 16);
}
// monotone float->uint mapping (handles tiny negative self-distances)
__device__ __forceinline__ uint ford(float f){
  uint u = __float_as_uint(f);
  return u ^ ((uint)((int)u >> 31) | 0x80000000u);
}

// ---------------- K0a: coords -> [n][l] float4 {x,y,z,|c|^2} ----------------
__global__ __launch_bounds__(256) void prep_coords(const float* __restrict__ coords,
                                                   float4* __restrict__ cF){
  int e = blockIdx.x * 256 + threadIdx.x;      // e = l*8+n, e < 65536
  int l = e >> 3, n = e & 7;
  const float* cr = coords + (size_t)e * 3;
  float x = cr[0], y = cr[1], z = cr[2];
  float cc;
  {
    #pragma clang fp contract(off)
    cc = x*x + y*y + z*z;                      // matches np sum(c*c,-1): (xx+yy)+zz
  }
  cF[n * L_ + l] = make_float4(x, y, z, cc);
}

// ---------------- K0b: keep_coords output (f32 gather, exact) ----------------
__global__ __launch_bounds__(256) void keep_coords_k(const float* __restrict__ coords,
                                                     const int* __restrict__ keep,
                                                     float* __restrict__ out0){
  int t = blockIdx.x * 256 + threadIdx.x;      // t < 49152 = L2*N*3
  int i = t / 24; int rem = t - i * 24;        // (n*3+c)
  out0[t] = coords[(size_t)keep[i] * 24 + rem];
}

// ---------------- K1: MLP (2 GEMMs + 2 LayerNorms + ReLU) for rows l<2048 ----------------
// block = 128 threads (one per output dim), 8 rows per block; row id rg = n*2048 + l
__device__ __forceinline__ float wsum(float v){
  #pragma unroll
  for (int o = 32; o; o >>= 1) v += __shfl_down(v, o, 64);
  return v;
}

__global__ __launch_bounds__(128) void mlp_k(const float* __restrict__ feat,
                                             const float* __restrict__ w1,
                                             const float* __restrict__ g1,
                                             const float* __restrict__ b1,
                                             const float* __restrict__ w2,
                                             const float* __restrict__ g2,
                                             const float* __restrict__ b2,
                                             ushort* __restrict__ fB){
  __shared__ float xs[8][64];
  __shared__ float hnl[8][128];
  __shared__ float part[2][2][8];  // [phase][wave][row]
  int tid = threadIdx.x, d = tid, wv = tid >> 6, lane = tid & 63;
  int rg0 = blockIdx.x * 8;

  // stage 8 input rows (64 f32 each) to LDS
  {
    int r = tid >> 4, k4 = tid & 15;
    int rg = rg0 + r; int l = rg & 2047, n = rg >> 11;
    const float4* src = (const float4*)(feat + (size_t)(l * 8 + n) * 64);
    *(float4*)&xs[r][k4 * 4] = src[k4];
  }
  __syncthreads();

  // GEMM1: h[r][d] = x[r] . w1[d]
  float acc[8];
  #pragma unroll
  for (int r = 0; r < 8; ++r) acc[r] = 0.f;
  {
    const float4* w1r = (const float4*)(w1 + (size_t)d * 64);
    #pragma unroll
    for (int k4 = 0; k4 < 16; ++k4){
      float4 wq = w1r[k4];
      #pragma unroll
      for (int r = 0; r < 8; ++r){
        float4 xv = *(const float4*)&xs[r][k4 * 4];
        acc[r] += xv.x*wq.x + xv.y*wq.y + xv.z*wq.z + xv.w*wq.w;
      }
    }
  }

  // LN1
  float g1d = g1[d], b1d = b1[d];
  #pragma unroll
  for (int r = 0; r < 8; ++r){ float s = wsum(acc[r]); if (lane == 0) part[0][wv][r] = s; }
  __syncthreads();
  float dv[8];
  #pragma unroll
  for (int r = 0; r < 8; ++r){
    float m = (part[0][0][r] + part[0][1][r]) * 0.0078125f;
    dv[r] = acc[r] - m;
  }
  #pragma unroll
  for (int r = 0; r < 8; ++r){ float s = wsum(dv[r]*dv[r]); if (lane == 0) part[1][wv][r] = s; }
  __syncthreads();
  #pragma unroll
  for (int r = 0; r < 8; ++r){
    float var = (part[1][0][r] + part[1][1][r]) * 0.0078125f;
    float rs = rsqrtf(var + 1e-5f);
    hnl[r][d] = dv[r] * rs * g1d + b1d;
  }
  __syncthreads();

  // GEMM2: h2[r][d] = hn[r] . w2[d]
  float a2[8];
  #pragma unroll
  for (int r = 0; r < 8; ++r) a2[r] = 0.f;
  {
    const float4* w2r = (const float4*)(w2 + (size_t)d * 128);
    #pragma unroll 8
    for (int k4 = 0; k4 < 32; ++k4){
      float4 wq = w2r[k4];
      #pragma unroll
      for (int r = 0; r < 8; ++r){
        float4 hv = *(const float4*)&hnl[r][k4 * 4];
        a2[r] += hv.x*wq.x + hv.y*wq.y + hv.z*wq.z + hv.w*wq.w;
      }
    }
  }

  // LN2 + ReLU + store bf16 (workspace intermediate; <=0.4% rel err, threshold 2%)
  float g2d = g2[d], b2d = b2[d];
  __syncthreads();  // protect part[] WAR
  #pragma unroll
  for (int r = 0; r < 8; ++r){ float s = wsum(a2[r]); if (lane == 0) part[0][wv][r] = s; }
  __syncthreads();
  #pragma unroll
  for (int r = 0; r < 8; ++r){
    float m = (part[0][0][r] + part[0][1][r]) * 0.0078125f;
    dv[r] = a2[r] - m;
  }
  #pragma unroll
  for (int r = 0; r < 8; ++r){ float s = wsum(dv[r]*dv[r]); if (lane == 0) part[1][wv][r] = s; }
  __syncthreads();
  #pragma unroll
  for (int r = 0; r < 8; ++r){
    float var = (part[1][0][r] + part[1][1][r]) * 0.0078125f;
    float rs = rsqrtf(var + 1e-5f);
    float o = dv[r] * rs * g2d + b2d;
    o = fmaxf(o, 0.f);
    fB[(size_t)(rg0 + r) * 128 + d] = f2b(o);
  }
}

// ---------------- K2: KNN top-16 (exact, stable) ----------------
// block = 512 (8 waves), 64 queries of one batch n. Wave w scans candidate slice
// [1024w,1024w+1024); lane = query (candidate coords wave-uniform). Pass1: per-lane
// value-only sorted-16 min/max network. Pass2: collect idx with d2<=tau into LDS.
// Merge: lane-per-query exact (ordered-d2,idx) top-16 with stable tie-break.
__global__ __launch_bounds__(512) void knn_k(const float4* __restrict__ cF,
                                             const int* __restrict__ keep,
                                             int* __restrict__ nn){
  __shared__ int lst[64 * 8 * CAP];   // 40 KB
  __shared__ int cnts[64 * 8];
  int tid = threadIdx.x;
  int lane = tid & 63;
  int w = __builtin_amdgcn_readfirstlane(tid >> 6);
  int qb = blockIdx.x << 6;                       // 64 queries/block; 32 blocks per n
  int n = __builtin_amdgcn_readfirstlane(qb >> 11);
  int i = (qb & 2047) + lane;
  int kidx = keep[i];
  float4 qf = cF[n * L_ + kidx];                  // query {x,y,z,kk}

  const float4* base = cF + n * L_ + (w << 10);

  // ---- pass 1: slice top-16 values ----
  float heap[16];
  #pragma unroll
  for (int j = 0; j < 16; ++j) heap[j] = 3.4e38f;
  float h15 = 3.4e38f;
  #pragma unroll 4
  for (int j = 0; j < 1024; ++j){
    float4 cf = base[j];
    float d2;
    {
      #pragma clang fp contract(off)
      float dot = qf.x*cf.x + qf.y*cf.y + qf.z*cf.z;
      d2 = (qf.w + cf.w) - 2.0f * dot;
    }
    if (d2 < h15){
      float x = d2;
      #pragma unroll
      for (int j2 = 0; j2 < 16; ++j2){
        float lo = fminf(heap[j2], x);
        x = fmaxf(heap[j2], x);
        heap[j2] = lo;
      }
      h15 = heap[15];
    }
  }

  // ---- pass 2: collect survivors (idx only) ----
  int cnt = 0;
  int lbase = (lane * 8 + w) * CAP;
  #pragma unroll 4
  for (int j = 0; j < 1024; ++j){
    float4 cf = base[j];
    float d2;
    {
      #pragma clang fp contract(off)
      float dot = qf.x*cf.x + qf.y*cf.y + qf.z*cf.z;
      d2 = (qf.w + cf.w) - 2.0f * dot;
    }
    if (d2 <= h15 && cnt < CAP){
      lst[lbase + cnt] = (w << 10) + j;
      cnt++;
    }
  }
  cnts[lane * 8 + w] = cnt;
  __syncthreads();

  // ---- merge: wave 0, lane q merges query qb+q ----
  if (tid < 64){
    u64 best[16];
    #pragma unroll
    for (int j = 0; j < 16; ++j) best[j] = ~0ull;
    u64 b15 = ~0ull;
    const float4* cbase = cF + n * L_;
    for (int s = 0; s < 8; ++s){
      int c = cnts[tid * 8 + s];
      int lb = (tid * 8 + s) * CAP;
      for (int e = 0; e < c; ++e){
        int idx = lst[lb + e];
        float4 cf = cbase[idx];
        float d2;
        {
          #pragma clang fp contract(off)
          float dot = qf.x*cf.x + qf.y*cf.y + qf.z*cf.z;
          d2 = (qf.w + cf.w) - 2.0f * dot;
        }
        u64 key = ((u64)ford(d2) << 32) | (uint)idx;
        if (key < b15){
          u64 x = key;
          #pragma unroll
          for (int j2 = 0; j2 < 16; ++j2){
            u64 lo = x < best[j2] ? x : best[j2];
            u64 hi = x < best[j2] ? best[j2] : x;
            best[j2] = lo; x = hi;
          }
          b15 = best[15];
        }
      }
    }
    int q = qb + tid;
    #pragma unroll
    for (int k = 0; k < 16; ++k)
      nn[q * 16 + k] = (int)(best[k] & 2047u);   // fmod(L2) quirk applied here
  }
}

// ---------------- K3: gather + max-pool (f32 output) ----------------
// one wave per query (i,n); lane covers 2 consecutive dims; gathers of 4B (bf16x2)
__global__ __launch_bounds__(256) void pool_k(const int* __restrict__ nn,
                                              const uint* __restrict__ fB32,
                                              float* __restrict__ out1){
  int tid = threadIdx.x; int lane = tid & 63;
  int qq = __builtin_amdgcn_readfirstlane(blockIdx.x * 4 + (tid >> 6)); // n*2048+i
  int n = qq >> 11, i = qq & 2047;
  const int* nnq = nn + qq * 16;
  float m0 = -3.4e38f, m1 = -3.4e38f;
  #pragma unroll
  for (int k = 0; k < 16; ++k){
    int l = nnq[k];
    uint u = fB32[(size_t)((n << 11) + l) * 64 + lane];
    float f0 = __uint_as_float((u & 0xFFFFu) << 16);
    float f1 = __uint_as_float((u >> 16) << 16);
    m0 = fmaxf(m0, f0); m1 = fmaxf(m1, f1);
  }
  // out1[i][n][dim], dim pair (2*lane, 2*lane+1) -> coalesced float2 store
  float2* o2 = (float2*)(out1 + (size_t)(i * 8 + n) * 128);
  o2[lane] = make_float2(m0, m1);
}

extern "C" void kernel_launch(void* const* d_in, const int* in_sizes, int n_in,
                              void* d_out, int out_size, void* d_ws, size_t ws_size,
                              hipStream_t stream){
  const float* coords = (const float*)d_in[0];
  const float* feat   = (const float*)d_in[1];
  const float* w1     = (const float*)d_in[2];
  const float* g1     = (const float*)d_in[3];
  const float* b1     = (const float*)d_in[4];
  const float* w2     = (const float*)d_in[5];
  const float* g2     = (const float*)d_in[6];
  const float* b2     = (const float*)d_in[7];
  const int*   keep   = (const int*)d_in[8];
  float* out0 = (float*)d_out;                    // keep_coords [2048,8,3]
  float* out1 = out0 + 49152;                     // pool_features [2048,8,128]

  char* ws = (char*)d_ws;
  float4* cF = (float4*)ws;                       // [N][L] f32x4 : 1 MB
  ushort* fB = (ushort*)(ws + (1 << 20));         // [N][L2][128] bf16 : 4 MB
  int*    nn = (int*)(ws + (5 << 20));            // [N][L2][16] i32 : 1 MB

  hipLaunchKernelGGL(prep_coords,   dim3(256),  dim3(256), 0, stream, coords, cF);
  hipLaunchKernelGGL(keep_coords_k, dim3(192),  dim3(256), 0, stream, coords, keep, out0);
  hipLaunchKernelGGL(mlp_k,         dim3(2048), dim3(128), 0, stream,
                     feat, w1, g1, b1, w2, g2, b2, fB);
  hipLaunchKernelGGL(knn_k,         dim3(256),  dim3(512), 0, stream, cF, keep, nn);
  hipLaunchKernelGGL(pool_k,        dim3(4096), dim3(256), 0, stream, nn, (const uint*)fB, out1);
}

// Round 4
// 470.326 us; speedup vs baseline: 1.1751x; 1.1751x over previous
//
#include <hip/hip_runtime.h>
#include <stdint.h>

// Problem constants
#define L_    8192
#define N_    8
#define L2_   2048
#define K_    16
#define CAP   20   // per-(query,slice) survivor capacity (16 + tie slack)
#define PEND  8    // pass-1 pending-buffer slots per lane

typedef unsigned int uint;
typedef unsigned short ushort;
typedef unsigned long long u64;

// round-to-nearest-even f32 -> bf16 (monotone)
__device__ __forceinline__ ushort f2b(float f){
  uint u = __float_as_uint(f);
  return (ushort)((u + 0x7FFFu + ((u >> 16) & 1u)) >> 16);
}
// monotone float->uint mapping (handles tiny negative self-distances)
__device__ __forceinline__ uint ford(float f){
  uint u = __float_as_uint(f);
  return u ^ ((uint)((int)u >> 31) | 0x80000000u);
}

// ---------------- K0a: coords -> [n][l] float4 {x,y,z,|c|^2} ----------------
__global__ __launch_bounds__(256) void prep_coords(const float* __restrict__ coords,
                                                   float4* __restrict__ cF){
  int e = blockIdx.x * 256 + threadIdx.x;      // e = l*8+n, e < 65536
  int l = e >> 3, n = e & 7;
  const float* cr = coords + (size_t)e * 3;
  float x = cr[0], y = cr[1], z = cr[2];
  float cc;
  {
    #pragma clang fp contract(off)
    cc = x*x + y*y + z*z;                      // matches np sum(c*c,-1): (xx+yy)+zz
  }
  cF[n * L_ + l] = make_float4(x, y, z, cc);
}

// ---------------- K0b: keep_coords output (f32 gather, exact) ----------------
__global__ __launch_bounds__(256) void keep_coords_k(const float* __restrict__ coords,
                                                     const int* __restrict__ keep,
                                                     float* __restrict__ out0){
  int t = blockIdx.x * 256 + threadIdx.x;      // t < 49152 = L2*N*3
  int i = t / 24; int rem = t - i * 24;        // (n*3+c)
  out0[t] = coords[(size_t)keep[i] * 24 + rem];
}

// ---------------- K1: MLP (2 GEMMs + 2 LayerNorms + ReLU) for rows l<2048 ----------------
__device__ __forceinline__ float wsum(float v){
  #pragma unroll
  for (int o = 32; o; o >>= 1) v += __shfl_down(v, o, 64);
  return v;
}

__global__ __launch_bounds__(128) void mlp_k(const float* __restrict__ feat,
                                             const float* __restrict__ w1,
                                             const float* __restrict__ g1,
                                             const float* __restrict__ b1,
                                             const float* __restrict__ w2,
                                             const float* __restrict__ g2,
                                             const float* __restrict__ b2,
                                             ushort* __restrict__ fB){
  __shared__ float xs[8][64];
  __shared__ float hnl[8][128];
  __shared__ float part[2][2][8];  // [phase][wave][row]
  int tid = threadIdx.x, d = tid, wv = tid >> 6, lane = tid & 63;
  int rg0 = blockIdx.x * 8;

  {
    int r = tid >> 4, k4 = tid & 15;
    int rg = rg0 + r; int l = rg & 2047, n = rg >> 11;
    const float4* src = (const float4*)(feat + (size_t)(l * 8 + n) * 64);
    *(float4*)&xs[r][k4 * 4] = src[k4];
  }
  __syncthreads();

  float acc[8];
  #pragma unroll
  for (int r = 0; r < 8; ++r) acc[r] = 0.f;
  {
    const float4* w1r = (const float4*)(w1 + (size_t)d * 64);
    #pragma unroll
    for (int k4 = 0; k4 < 16; ++k4){
      float4 wq = w1r[k4];
      #pragma unroll
      for (int r = 0; r < 8; ++r){
        float4 xv = *(const float4*)&xs[r][k4 * 4];
        acc[r] += xv.x*wq.x + xv.y*wq.y + xv.z*wq.z + xv.w*wq.w;
      }
    }
  }

  float g1d = g1[d], b1d = b1[d];
  #pragma unroll
  for (int r = 0; r < 8; ++r){ float s = wsum(acc[r]); if (lane == 0) part[0][wv][r] = s; }
  __syncthreads();
  float dv[8];
  #pragma unroll
  for (int r = 0; r < 8; ++r){
    float m = (part[0][0][r] + part[0][1][r]) * 0.0078125f;
    dv[r] = acc[r] - m;
  }
  #pragma unroll
  for (int r = 0; r < 8; ++r){ float s = wsum(dv[r]*dv[r]); if (lane == 0) part[1][wv][r] = s; }
  __syncthreads();
  #pragma unroll
  for (int r = 0; r < 8; ++r){
    float var = (part[1][0][r] + part[1][1][r]) * 0.0078125f;
    float rs = rsqrtf(var + 1e-5f);
    hnl[r][d] = dv[r] * rs * g1d + b1d;
  }
  __syncthreads();

  float a2[8];
  #pragma unroll
  for (int r = 0; r < 8; ++r) a2[r] = 0.f;
  {
    const float4* w2r = (const float4*)(w2 + (size_t)d * 128);
    #pragma unroll 8
    for (int k4 = 0; k4 < 32; ++k4){
      float4 wq = w2r[k4];
      #pragma unroll
      for (int r = 0; r < 8; ++r){
        float4 hv = *(const float4*)&hnl[r][k4 * 4];
        a2[r] += hv.x*wq.x + hv.y*wq.y + hv.z*wq.z + hv.w*wq.w;
      }
    }
  }

  float g2d = g2[d], b2d = b2[d];
  __syncthreads();
  #pragma unroll
  for (int r = 0; r < 8; ++r){ float s = wsum(a2[r]); if (lane == 0) part[0][wv][r] = s; }
  __syncthreads();
  #pragma unroll
  for (int r = 0; r < 8; ++r){
    float m = (part[0][0][r] + part[0][1][r]) * 0.0078125f;
    dv[r] = a2[r] - m;
  }
  #pragma unroll
  for (int r = 0; r < 8; ++r){ float s = wsum(dv[r]*dv[r]); if (lane == 0) part[1][wv][r] = s; }
  __syncthreads();
  #pragma unroll
  for (int r = 0; r < 8; ++r){
    float var = (part[1][0][r] + part[1][1][r]) * 0.0078125f;
    float rs = rsqrtf(var + 1e-5f);
    float o = dv[r] * rs * g2d + b2d;
    o = fmaxf(o, 0.f);
    fB[(size_t)(rg0 + r) * 128 + d] = f2b(o);
  }
}

// ---------------- K2: KNN top-16 (exact, stable, defer-buffer selection) ----------------
// block = 1024 (16 waves) = 64 queries; wave w scans slice [512w, 512w+512).
// Pass 1: per-lane exact top-16 VALUES via pending-buffer (append survivors cheap;
// batch the insertion network behind __any(pc==PEND) so it runs ~10x less often).
// Pass 2: collect slice-local idx (u16) with d2<=h into LDS (reuses pend region).
// Merge: wave 0, lane q: exact (ford(d2),idx) top-16 with stable tie-break.
__global__ __launch_bounds__(1024) void knn_k(const float4* __restrict__ cF,
                                              const int* __restrict__ keep,
                                              int* __restrict__ nn){
  __shared__ uint buf[10240];          // 40KB union: pass1 pend f32 (stride 9/lane), pass2 lst u16
  __shared__ int cnts[64 * 16];        // 4KB
  int tid = threadIdx.x;
  int lane = tid & 63;
  int w = __builtin_amdgcn_readfirstlane(tid >> 6);   // slice 0..15
  int qb = blockIdx.x << 6;                           // 64 queries/block; grid 256
  int n = __builtin_amdgcn_readfirstlane(qb >> 11);
  int i = (qb & 2047) + lane;
  int kidx = keep[i];
  float4 qf = cF[n * L_ + kidx];                      // query {x,y,z,kk}

  const float4* base = cF + n * L_ + (w << 9);

  // ---- pass 1: exact slice top-16 values (defer-buffer) ----
  float* pend = (float*)buf + tid * 9;                // stride 9 breaks bank alignment
  float best[16];
  #pragma unroll
  for (int j = 0; j < 16; ++j) best[j] = 3.4e38f;
  float h = 3.4e38f;
  int pc = 0;
  #pragma unroll 4
  for (int j = 0; j < 512; ++j){
    float4 cf = base[j];
    float d2;
    {
      #pragma clang fp contract(off)
      float dot = qf.x*cf.x + qf.y*cf.y + qf.z*cf.z;
      d2 = (qf.w + cf.w) - 2.0f * dot;
    }
    if (d2 < h){ pend[pc] = d2; pc++; }
    if (__any(pc == PEND)){
      for (int e = 0; e < pc; ++e){
        float x = pend[e];
        #pragma unroll
        for (int j2 = 0; j2 < 16; ++j2){
          float lo = fminf(best[j2], x);
          x = fmaxf(best[j2], x);
          best[j2] = lo;
        }
      }
      pc = 0; h = best[15];
    }
  }
  // final drain
  for (int e = 0; e < pc; ++e){
    float x = pend[e];
    #pragma unroll
    for (int j2 = 0; j2 < 16; ++j2){
      float lo = fminf(best[j2], x);
      x = fmaxf(best[j2], x);
      best[j2] = lo;
    }
  }
  h = best[15];                                       // exact slice 16th-smallest
  __syncthreads();                                    // pend dead before lst writes

  // ---- pass 2: collect survivors (slice-local idx, u16) ----
  ushort* lst = (ushort*)buf;
  int cnt = 0;
  int lb = (lane * 16 + w) * CAP;
  #pragma unroll 4
  for (int j = 0; j < 512; ++j){
    float4 cf = base[j];
    float d2;
    {
      #pragma clang fp contract(off)
      float dot = qf.x*cf.x + qf.y*cf.y + qf.z*cf.z;
      d2 = (qf.w + cf.w) - 2.0f * dot;
    }
    if (d2 <= h && cnt < CAP){
      lst[lb + cnt] = (ushort)j;
      cnt++;
    }
  }
  cnts[lane * 16 + w] = cnt;
  __syncthreads();

  // ---- merge: wave 0, lane q merges query qb+q across 16 slices ----
  if (tid < 64){
    u64 best64[16];
    #pragma unroll
    for (int j = 0; j < 16; ++j) best64[j] = ~0ull;
    u64 b15 = ~0ull;
    const float4* cbase = cF + n * L_;
    for (int s = 0; s < 16; ++s){
      int c = cnts[tid * 16 + s];
      int lb2 = (tid * 16 + s) * CAP;
      for (int e = 0; e < c; ++e){
        int idx = (s << 9) + (int)lst[lb2 + e];
        float4 cf = cbase[idx];
        float d2;
        {
          #pragma clang fp contract(off)
          float dot = qf.x*cf.x + qf.y*cf.y + qf.z*cf.z;
          d2 = (qf.w + cf.w) - 2.0f * dot;
        }
        u64 key = ((u64)ford(d2) << 32) | (uint)idx;
        if (key < b15){
          u64 x = key;
          #pragma unroll
          for (int j2 = 0; j2 < 16; ++j2){
            u64 lo = x < best64[j2] ? x : best64[j2];
            u64 hi = x < best64[j2] ? best64[j2] : x;
            best64[j2] = lo; x = hi;
          }
          b15 = best64[15];
        }
      }
    }
    int q = qb + tid;
    #pragma unroll
    for (int k = 0; k < 16; ++k)
      nn[q * 16 + k] = (int)(best64[k] & 2047u);      // fmod(L2) quirk
  }
}

// ---------------- K3: gather + max-pool (f32 output) ----------------
__global__ __launch_bounds__(256) void pool_k(const int* __restrict__ nn,
                                              const uint* __restrict__ fB32,
                                              float* __restrict__ out1){
  int tid = threadIdx.x; int lane = tid & 63;
  int qq = __builtin_amdgcn_readfirstlane(blockIdx.x * 4 + (tid >> 6)); // n*2048+i
  int n = qq >> 11, i = qq & 2047;
  const int* nnq = nn + qq * 16;
  float m0 = -3.4e38f, m1 = -3.4e38f;
  #pragma unroll
  for (int k = 0; k < 16; ++k){
    int l = nnq[k];
    uint u = fB32[(size_t)((n << 11) + l) * 64 + lane];
    float f0 = __uint_as_float((u & 0xFFFFu) << 16);
    float f1 = __uint_as_float((u >> 16) << 16);
    m0 = fmaxf(m0, f0); m1 = fmaxf(m1, f1);
  }
  float2* o2 = (float2*)(out1 + (size_t)(i * 8 + n) * 128);
  o2[lane] = make_float2(m0, m1);
}

extern "C" void kernel_launch(void* const* d_in, const int* in_sizes, int n_in,
                              void* d_out, int out_size, void* d_ws, size_t ws_size,
                              hipStream_t stream){
  const float* coords = (const float*)d_in[0];
  const float* feat   = (const float*)d_in[1];
  const float* w1     = (const float*)d_in[2];
  const float* g1     = (const float*)d_in[3];
  const float* b1     = (const float*)d_in[4];
  const float* w2     = (const float*)d_in[5];
  const float* g2     = (const float*)d_in[6];
  const float* b2     = (const float*)d_in[7];
  const int*   keep   = (const int*)d_in[8];
  float* out0 = (float*)d_out;                    // keep_coords [2048,8,3]
  float* out1 = out0 + 49152;                     // pool_features [2048,8,128]

  char* ws = (char*)d_ws;
  float4* cF = (float4*)ws;                       // [N][L] f32x4 : 1 MB
  ushort* fB = (ushort*)(ws + (1 << 20));         // [N][L2][128] bf16 : 4 MB
  int*    nn = (int*)(ws + (5 << 20));            // [N][L2][16] i32 : 1 MB

  hipLaunchKernelGGL(prep_coords,   dim3(256),  dim3(256), 0, stream, coords, cF);
  hipLaunchKernelGGL(keep_coords_k, dim3(192),  dim3(256), 0, stream, coords, keep, out0);
  hipLaunchKernelGGL(mlp_k,         dim3(2048), dim3(128), 0, stream,
                     feat, w1, g1, b1, w2, g2, b2, fB);
  hipLaunchKernelGGL(knn_k,         dim3(256),  dim3(1024), 0, stream, cF, keep, nn);
  hipLaunchKernelGGL(pool_k,        dim3(4096), dim3(256), 0, stream, nn, (const uint*)fB, out1);
}

// Round 5
// 265.425 us; speedup vs baseline: 2.0823x; 1.7720x over previous
//
#include <hip/hip_runtime.h>
#include <stdint.h>

// Problem constants
#define L_    8192
#define N_    8
#define L2_   2048
#define K_    16

typedef unsigned int uint;
typedef unsigned short ushort;
typedef unsigned long long u64;

// round-to-nearest-even f32 -> bf16 (monotone)
__device__ __forceinline__ ushort f2b(float f){
  uint u = __float_as_uint(f);
  return (ushort)((u + 0x7FFFu + ((u >> 16) & 1u)) >> 16);
}
// monotone float->uint mapping (handles tiny negative self-distances)
__device__ __forceinline__ uint ford(float f){
  uint u = __float_as_uint(f);
  return u ^ ((uint)((int)u >> 31) | 0x80000000u);
}

// ---------------- K0a: coords -> [n][l] float4 {x,y,z,|c|^2} ----------------
__global__ __launch_bounds__(256) void prep_coords(const float* __restrict__ coords,
                                                   float4* __restrict__ cF){
  int e = blockIdx.x * 256 + threadIdx.x;      // e = l*8+n, e < 65536
  int l = e >> 3, n = e & 7;
  const float* cr = coords + (size_t)e * 3;
  float x = cr[0], y = cr[1], z = cr[2];
  float cc;
  {
    #pragma clang fp contract(off)
    cc = x*x + y*y + z*z;                      // matches np sum(c*c,-1): (xx+yy)+zz
  }
  cF[n * L_ + l] = make_float4(x, y, z, cc);
}

// ---------------- K0b: keep_coords output (f32 gather, exact) ----------------
__global__ __launch_bounds__(256) void keep_coords_k(const float* __restrict__ coords,
                                                     const int* __restrict__ keep,
                                                     float* __restrict__ out0){
  int t = blockIdx.x * 256 + threadIdx.x;      // t < 49152 = L2*N*3
  int i = t / 24; int rem = t - i * 24;        // (n*3+c)
  out0[t] = coords[(size_t)keep[i] * 24 + rem];
}

// ---------------- K1: MLP (2 GEMMs + 2 LayerNorms + ReLU) for rows l<2048 ----------------
__device__ __forceinline__ float wsum(float v){
  #pragma unroll
  for (int o = 32; o; o >>= 1) v += __shfl_down(v, o, 64);
  return v;
}

__global__ __launch_bounds__(128) void mlp_k(const float* __restrict__ feat,
                                             const float* __restrict__ w1,
                                             const float* __restrict__ g1,
                                             const float* __restrict__ b1,
                                             const float* __restrict__ w2,
                                             const float* __restrict__ g2,
                                             const float* __restrict__ b2,
                                             ushort* __restrict__ fB){
  __shared__ float xs[8][64];
  __shared__ float hnl[8][128];
  __shared__ float part[2][2][8];  // [phase][wave][row]
  int tid = threadIdx.x, d = tid, wv = tid >> 6, lane = tid & 63;
  int rg0 = blockIdx.x * 8;

  {
    int r = tid >> 4, k4 = tid & 15;
    int rg = rg0 + r; int l = rg & 2047, n = rg >> 11;
    const float4* src = (const float4*)(feat + (size_t)(l * 8 + n) * 64);
    *(float4*)&xs[r][k4 * 4] = src[k4];
  }
  __syncthreads();

  float acc[8];
  #pragma unroll
  for (int r = 0; r < 8; ++r) acc[r] = 0.f;
  {
    const float4* w1r = (const float4*)(w1 + (size_t)d * 64);
    #pragma unroll
    for (int k4 = 0; k4 < 16; ++k4){
      float4 wq = w1r[k4];
      #pragma unroll
      for (int r = 0; r < 8; ++r){
        float4 xv = *(const float4*)&xs[r][k4 * 4];
        acc[r] += xv.x*wq.x + xv.y*wq.y + xv.z*wq.z + xv.w*wq.w;
      }
    }
  }

  float g1d = g1[d], b1d = b1[d];
  #pragma unroll
  for (int r = 0; r < 8; ++r){ float s = wsum(acc[r]); if (lane == 0) part[0][wv][r] = s; }
  __syncthreads();
  float dv[8];
  #pragma unroll
  for (int r = 0; r < 8; ++r){
    float m = (part[0][0][r] + part[0][1][r]) * 0.0078125f;
    dv[r] = acc[r] - m;
  }
  #pragma unroll
  for (int r = 0; r < 8; ++r){ float s = wsum(dv[r]*dv[r]); if (lane == 0) part[1][wv][r] = s; }
  __syncthreads();
  #pragma unroll
  for (int r = 0; r < 8; ++r){
    float var = (part[1][0][r] + part[1][1][r]) * 0.0078125f;
    float rs = rsqrtf(var + 1e-5f);
    hnl[r][d] = dv[r] * rs * g1d + b1d;
  }
  __syncthreads();

  float a2[8];
  #pragma unroll
  for (int r = 0; r < 8; ++r) a2[r] = 0.f;
  {
    const float4* w2r = (const float4*)(w2 + (size_t)d * 128);
    #pragma unroll 8
    for (int k4 = 0; k4 < 32; ++k4){
      float4 wq = w2r[k4];
      #pragma unroll
      for (int r = 0; r < 8; ++r){
        float4 hv = *(const float4*)&hnl[r][k4 * 4];
        a2[r] += hv.x*wq.x + hv.y*wq.y + hv.z*wq.z + hv.w*wq.w;
      }
    }
  }

  float g2d = g2[d], b2d = b2[d];
  __syncthreads();
  #pragma unroll
  for (int r = 0; r < 8; ++r){ float s = wsum(a2[r]); if (lane == 0) part[0][wv][r] = s; }
  __syncthreads();
  #pragma unroll
  for (int r = 0; r < 8; ++r){
    float m = (part[0][0][r] + part[0][1][r]) * 0.0078125f;
    dv[r] = a2[r] - m;
  }
  #pragma unroll
  for (int r = 0; r < 8; ++r){ float s = wsum(dv[r]*dv[r]); if (lane == 0) part[1][wv][r] = s; }
  __syncthreads();
  #pragma unroll
  for (int r = 0; r < 8; ++r){
    float var = (part[1][0][r] + part[1][1][r]) * 0.0078125f;
    float rs = rsqrtf(var + 1e-5f);
    float o = dv[r] * rs * g2d + b2d;
    o = fmaxf(o, 0.f);
    fB[(size_t)(rg0 + r) * 128 + d] = f2b(o);
  }
}

// ---------------- K2: KNN top-16 (wave-per-query, ballot-compact + bitonic) ----------------
__device__ __forceinline__ u64 shfl64(u64 v, int src){
  int lo = __shfl((int)(uint)v, src, 64);
  int hi = __shfl((int)(uint)(v >> 32), src, 64);
  return ((u64)(uint)hi << 32) | (uint)lo;
}

// full ascending bitonic sort of 64 u64 keys (one per lane)
__device__ __forceinline__ u64 bsort64(u64 key, int lane){
  #pragma unroll
  for (int k = 2; k <= 64; k <<= 1){
    #pragma unroll
    for (int j = k >> 1; j > 0; j >>= 1){
      u64 o = shfl64(key, lane ^ j);
      bool lower = (lane & j) == 0;
      bool down  = (lane & k) == 0;     // ascending block (k=64: all ascending)
      bool takeMin = (lower == down);
      bool oLess = o < key;
      key = (oLess == takeMin) ? o : key;
    }
  }
  return key;
}
// ascending merge of a bitonic 64-sequence
__device__ __forceinline__ u64 bmerge64(u64 key, int lane){
  #pragma unroll
  for (int j = 32; j > 0; j >>= 1){
    u64 o = shfl64(key, lane ^ j);
    bool lower = (lane & j) == 0;
    bool oLess = o < key;
    key = (oLess == lower) ? o : key;
  }
  return key;
}

// re-select exact top-16 from the queue (qcount <= 112), tighten h, compact to 16
__device__ __forceinline__ void drain(u64* ldsq, int& qcount, u64& h, int lane){
  u64 a = ldsq[lane];
  if (lane >= qcount) a = ~0ull;
  if (qcount > 64){
    u64 b = ldsq[64 + lane];
    if (64 + lane >= qcount) b = ~0ull;
    a = bsort64(a, lane);
    b = bsort64(b, lane);
    u64 br = shfl64(b, 63 - lane);      // concat(A asc, rev(B asc)) is bitonic
    a = a < br ? a : br;                // lower-64 multiset, bitonic
    a = bmerge64(a, lane);
  } else {
    a = bsort64(a, lane);
  }
  if (lane < 16) ldsq[lane] = a;
  h = shfl64(a, 15);                    // exact 16th-smallest key so far
  qcount = 16;
}

// block = 256 (4 waves); wave = one query g = blockIdx*4+wv; lane = candidate-in-batch
__global__ __launch_bounds__(256) void knn_k(const float4* __restrict__ cF,
                                             const int* __restrict__ keep,
                                             int* __restrict__ nn){
  __shared__ u64 q8[4][128];            // 4 KB: per-wave survivor queue
  int tid = threadIdx.x, lane = tid & 63;
  int wv = tid >> 6;
  int g = blockIdx.x * 4 + wv;          // query id 0..16383
  int n = g >> 11, i = g & 2047;
  u64* ldsq = q8[wv];
  int kidx = keep[i];
  float4 qf = cF[(n << 13) + kidx];     // wave-uniform query {x,y,z,kk}
  const float4* base = cF + (n << 13);

  u64 h = ~0ull;
  int qcount = 0;
  #pragma unroll 2
  for (int b = 0; b < 128; ++b){
    int j = (b << 6) + lane;
    float4 cf = base[j];                // coalesced dwordx4
    float d2;
    {
      #pragma clang fp contract(off)
      float dot = qf.x*cf.x + qf.y*cf.y + qf.z*cf.z;
      d2 = (qf.w + cf.w) - 2.0f * dot;
    }
    u64 key = ((u64)ford(d2) << 32) | (uint)j;
    bool pred = key < h;
    u64 bal = __ballot(pred);
    if (bal){
      if (pred){
        int rel = __builtin_amdgcn_mbcnt_lo((uint)bal, 0);
        rel = __builtin_amdgcn_mbcnt_hi((uint)(bal >> 32), rel);
        ldsq[qcount + rel] = key;
      }
      qcount += __popcll(bal);
      if (qcount >= 49) drain(ldsq, qcount, h, lane);   // capacity: 48+64 <= 128
    }
  }
  drain(ldsq, qcount, h, lane);
  if (lane < 16){
    u64 a = ldsq[lane];
    nn[g * 16 + lane] = (int)(a & 2047u);   // fmod(L2) quirk
  }
}

// ---------------- K3: gather + max-pool (f32 output) ----------------
__global__ __launch_bounds__(256) void pool_k(const int* __restrict__ nn,
                                              const uint* __restrict__ fB32,
                                              float* __restrict__ out1){
  int tid = threadIdx.x; int lane = tid & 63;
  int qq = __builtin_amdgcn_readfirstlane(blockIdx.x * 4 + (tid >> 6)); // n*2048+i
  int n = qq >> 11, i = qq & 2047;
  const int* nnq = nn + qq * 16;
  float m0 = -3.4e38f, m1 = -3.4e38f;
  #pragma unroll
  for (int k = 0; k < 16; ++k){
    int l = nnq[k];
    uint u = fB32[(size_t)((n << 11) + l) * 64 + lane];
    float f0 = __uint_as_float((u & 0xFFFFu) << 16);
    float f1 = __uint_as_float((u >> 16) << 16);
    m0 = fmaxf(m0, f0); m1 = fmaxf(m1, f1);
  }
  float2* o2 = (float2*)(out1 + (size_t)(i * 8 + n) * 128);
  o2[lane] = make_float2(m0, m1);
}

extern "C" void kernel_launch(void* const* d_in, const int* in_sizes, int n_in,
                              void* d_out, int out_size, void* d_ws, size_t ws_size,
                              hipStream_t stream){
  const float* coords = (const float*)d_in[0];
  const float* feat   = (const float*)d_in[1];
  const float* w1     = (const float*)d_in[2];
  const float* g1     = (const float*)d_in[3];
  const float* b1     = (const float*)d_in[4];
  const float* w2     = (const float*)d_in[5];
  const float* g2     = (const float*)d_in[6];
  const float* b2     = (const float*)d_in[7];
  const int*   keep   = (const int*)d_in[8];
  float* out0 = (float*)d_out;                    // keep_coords [2048,8,3]
  float* out1 = out0 + 49152;                     // pool_features [2048,8,128]

  char* ws = (char*)d_ws;
  float4* cF = (float4*)ws;                       // [N][L] f32x4 : 1 MB
  ushort* fB = (ushort*)(ws + (1 << 20));         // [N][L2][128] bf16 : 4 MB
  int*    nn = (int*)(ws + (5 << 20));            // [N][L2][16] i32 : 1 MB

  hipLaunchKernelGGL(prep_coords,   dim3(256),  dim3(256), 0, stream, coords, cF);
  hipLaunchKernelGGL(keep_coords_k, dim3(192),  dim3(256), 0, stream, coords, keep, out0);
  hipLaunchKernelGGL(mlp_k,         dim3(2048), dim3(128), 0, stream,
                     feat, w1, g1, b1, w2, g2, b2, fB);
  hipLaunchKernelGGL(knn_k,         dim3(4096), dim3(256), 0, stream, cF, keep, nn);
  hipLaunchKernelGGL(pool_k,        dim3(4096), dim3(256), 0, stream, nn, (const uint*)fB, out1);
}